// Round 5
// baseline (404.223 us; speedup 1.0000x reference)
//
#include <hip/hip_runtime.h>
#include <hip/hip_bf16.h>

#define HC 256

typedef __attribute__((ext_vector_type(8))) short bf16x8;
typedef __attribute__((ext_vector_type(4))) float f32x4;

// ======== split fp32 -> (hi|lo) bf16, K-concat layouts =====================
// A2[row][2F]: cols [0,F)=hi, [F,2F)=lo
__global__ void k_split_x(const float* __restrict__ x, ushort* __restrict__ A2,
                          int n, int F) {
  int idx = blockIdx.x * blockDim.x + threadIdx.x;  // one per 4 elements
  int total = n * F / 4;
  if (idx >= total) return;
  int fq = F / 4;
  int row = idx / fq, q = idx - row * fq;
  float4 v = ((const float4*)x)[idx];
  float vv[4] = {v.x, v.y, v.z, v.w};
  ushort hb[4], lb[4];
#pragma unroll
  for (int j = 0; j < 4; ++j) {
    __hip_bfloat16 h = __float2bfloat16(vv[j]);
    hb[j] = *(ushort*)&h;
    __hip_bfloat16 l = __float2bfloat16(vv[j] - __bfloat162float(h));
    lb[j] = *(ushort*)&l;
  }
  ushort* rp = A2 + (size_t)row * 2 * F;
  *(ushort4*)(rp + q * 4) = make_ushort4(hb[0], hb[1], hb[2], hb[3]);
  *(ushort4*)(rp + F + q * 4) = make_ushort4(lb[0], lb[1], lb[2], lb[3]);
}

// WT[col][3F]: col<256 from Wl, col>=256 from Wr; k-blocks hi|lo|hi
__global__ void k_split_w(const float* __restrict__ Wl, const float* __restrict__ Wr,
                          ushort* __restrict__ WT, int F) {
  int idx = blockIdx.x * blockDim.x + threadIdx.x;
  if (idx >= 512 * F) return;
  int col = idx / F, f = idx - col * F;
  float v = (col < 256) ? Wl[col * F + f] : Wr[(col - 256) * F + f];
  __hip_bfloat16 h = __float2bfloat16(v);
  __hip_bfloat16 l = __float2bfloat16(v - __bfloat162float(h));
  ushort* row = WT + (size_t)col * 3 * F;
  row[f] = *(ushort*)&h;
  row[F + f] = *(ushort*)&l;
  row[2 * F + f] = *(ushort*)&h;
}

// ======== MFMA GEMM ========================================================
// D = A_hi*B_hi + A_hi*B_lo + A_lo*B_hi via K-concat (Khat = 3F).
// Block: 256 thr = 4 waves; tile 128(M) x 128(N), BK=32. Wave owns 32x128.
// Cols 0..255 (xl) are emitted as bf16 into xlb[n][256] (gather operand);
// cols 256..511 (xr) as fp32 into xr[n][256].
template <int F>
__global__ __launch_bounds__(256) void gemm_mfma(const ushort* __restrict__ A2,
                                                 const ushort* __restrict__ WT,
                                                 ushort* __restrict__ xlb,
                                                 float* __restrict__ xr, int n_nodes) {
  constexpr int KC = 3 * F;
  constexpr int NSTEP = KC / 32;
  constexpr int PITCH = 40;
  __shared__ __align__(16) ushort As[128 * PITCH];
  __shared__ __align__(16) ushort Bs[128 * PITCH];
  const int tid = threadIdx.x;
  const int wv = tid >> 6, lane = tid & 63;
  const int m16 = lane & 15, quad = lane >> 4;
  const int row0 = blockIdx.x * 128;
  const int col0 = blockIdx.y * 128;

  f32x4 acc[2][8];
#pragma unroll
  for (int i = 0; i < 2; ++i)
#pragma unroll
    for (int j = 0; j < 8; ++j) acc[i][j] = (f32x4){0.f, 0.f, 0.f, 0.f};

  for (int s = 0; s < NSTEP; ++s) {
    const int khat = s * 32;
    const int asrc = (khat < F) ? khat : khat - F;  // hi|hi|lo source column
    __syncthreads();
#pragma unroll
    for (int c = 0; c < 2; ++c) {
      int u = tid + 256 * c;  // 512 16B-chunks per tile
      int r = u >> 2, ch = u & 3;
      int grow = row0 + r;
      int4 aval = {0, 0, 0, 0};
      if (grow < n_nodes)
        aval = *(const int4*)(A2 + (size_t)grow * (2 * F) + asrc + ch * 8);
      *(int4*)&As[r * PITCH + ch * 8] = aval;
      int4 bval = *(const int4*)(WT + (size_t)(col0 + r) * KC + khat + ch * 8);
      *(int4*)&Bs[r * PITCH + ch * 8] = bval;
    }
    __syncthreads();
    bf16x8 af[2];
#pragma unroll
    for (int i = 0; i < 2; ++i)
      af[i] = *(bf16x8*)&As[(wv * 32 + i * 16 + m16) * PITCH + quad * 8];
#pragma unroll
    for (int j = 0; j < 8; ++j) {
      bf16x8 bf = *(bf16x8*)&Bs[(j * 16 + m16) * PITCH + quad * 8];
      acc[0][j] = __builtin_amdgcn_mfma_f32_16x16x32_bf16(af[0], bf, acc[0][j], 0, 0, 0);
      acc[1][j] = __builtin_amdgcn_mfma_f32_16x16x32_bf16(af[1], bf, acc[1][j], 0, 0, 0);
    }
  }
  // epilogue: C/D layout col=lane&15, row=quad*4+reg
  const bool is_xl = (col0 < 256);
#pragma unroll
  for (int i = 0; i < 2; ++i) {
#pragma unroll
    for (int r = 0; r < 4; ++r) {
      int grow = row0 + wv * 32 + i * 16 + quad * 4 + r;
      if (grow < n_nodes) {
#pragma unroll
        for (int j = 0; j < 8; ++j) {
          float v = acc[i][j][r];
          int col = col0 + j * 16 + m16;
          if (is_xl) {
            __hip_bfloat16 h = __float2bfloat16(v);
            xlb[(size_t)grow * 256 + col] = *(ushort*)&h;
          } else {
            xr[(size_t)grow * 256 + (col - 256)] = v;
          }
        }
      }
    }
  }
}

// ================= CSR build (edges bucketed by dst) =======================
__global__ void k_hist(const int* __restrict__ ei, int* __restrict__ deg, int E_) {
  int e = blockIdx.x * blockDim.x + threadIdx.x;
  if (e < E_) atomicAdd(&deg[ei[E_ + e]], 1);
}

__global__ void k_scan_local(const int* __restrict__ deg, int* __restrict__ rowstart,
                             int* __restrict__ partial, int n) {
  __shared__ int a[256], b[256];
  const int t = threadIdx.x;
  const int i = blockIdx.x * 256 + t;
  const int v = (i < n) ? deg[i] : 0;
  a[t] = v;
  __syncthreads();
  int* cur = a;
  int* nxt = b;
  for (int off = 1; off < 256; off <<= 1) {
    int x = cur[t];
    if (t >= off) x += cur[t - off];
    nxt[t] = x;
    __syncthreads();
    int* tmp = cur; cur = nxt; nxt = tmp;
  }
  const int incl = cur[t];
  if (i < n) rowstart[i] = incl - v;
  if (t == 255) partial[blockIdx.x] = incl;
}

__global__ void k_scan_partial(int* __restrict__ partial, int nblk) {
  __shared__ int a[256], b[256];
  const int t = threadIdx.x;
  const int v = (t < nblk) ? partial[t] : 0;
  a[t] = v;
  __syncthreads();
  int* cur = a;
  int* nxt = b;
  for (int off = 1; off < 256; off <<= 1) {
    int x = cur[t];
    if (t >= off) x += cur[t - off];
    nxt[t] = x;
    __syncthreads();
    int* tmp = cur; cur = nxt; nxt = tmp;
  }
  if (t < nblk) partial[t] = cur[t] - v;
}

__global__ void k_add_off(int* __restrict__ rowstart, const int* __restrict__ partial,
                          int n, int E_) {
  int i = blockIdx.x * blockDim.x + threadIdx.x;
  if (i < n) rowstart[i] += partial[i >> 8];
  if (i == 0) rowstart[n] = E_;
}

__global__ void k_scatter(const int* __restrict__ ei, const float* __restrict__ ea,
                          int* __restrict__ cursor, int* __restrict__ ssrc,
                          float4* __restrict__ sea, int E_) {
  int e = blockIdx.x * blockDim.x + threadIdx.x;
  if (e < E_) {
    int dst = ei[E_ + e];
    int pos = atomicAdd(&cursor[dst], 1);
    ssrc[pos] = ei[e];
    sea[pos] = make_float4(ea[e * 3], ea[e * 3 + 1], ea[e * 3 + 2], 0.f);
  }
}

// ================= fused per-destination attention =========================
// One wave per dst node. Lane l owns channels 4l..4l+3 (head = l/16).
// xl gathered as bf16 (512 B/edge); xr streamed fp32. 2-deep src prefetch
// breaks the ssrc->row dependent chain. No atomics, online softmax.
template <bool PRELU>
__global__ __launch_bounds__(256) void fused_attn(
    const ushort* __restrict__ xlb, const float* __restrict__ xr,
    const int* __restrict__ rowstart, const int* __restrict__ ssrc,
    const float4* __restrict__ sea, const float* __restrict__ We,
    const float* __restrict__ att, const float* __restrict__ bias,
    const float* __restrict__ pw, float* __restrict__ out, int n) {
  const int lane = threadIdx.x & 63;
  const int d = (blockIdx.x * blockDim.x + threadIdx.x) >> 6;
  if (d >= n) return;
  float we0[4], we1[4], we2[4], at[4];
#pragma unroll
  for (int j = 0; j < 4; ++j) {
    int r = 4 * lane + j;
    we0[j] = We[r * 3 + 0];
    we1[j] = We[r * 3 + 1];
    we2[j] = We[r * 3 + 2];
    at[j] = att[r];
  }
  const ushort4* xlb4 = (const ushort4*)xlb;
  const float4 xrv = ((const float4*)xr)[(size_t)d * 64 + lane];

  int pos = rowstart[d];
  const int end = rowstart[d + 1];
  float num0 = 0.f, num1 = 0.f, num2 = 0.f, num3 = 0.f;
  float den = 0.f;

  // pipeline: luA/eaA for edge p (in flight), srcB for edge p+1
  ushort4 luA = {0, 0, 0, 0};
  float4 eaA = {0.f, 0.f, 0.f, 0.f};
  int srcB = 0;
  if (pos < end) {
    int srcA = ssrc[pos];
    luA = xlb4[(size_t)srcA * 64 + lane];
    eaA = sea[pos];
  }
  if (pos + 1 < end) srcB = ssrc[pos + 1];

  while (pos < end) {
    // issue next edge's loads (src already known), and src two ahead
    ushort4 luB = {0, 0, 0, 0};
    float4 eaB = {0.f, 0.f, 0.f, 0.f};
    if (pos + 1 < end) {
      luB = xlb4[(size_t)srcB * 64 + lane];
      eaB = sea[pos + 1];
    }
    int srcC = 0;
    if (pos + 2 < end) srcC = ssrc[pos + 2];

    float lav[4];
    lav[0] = __uint_as_float((unsigned)luA.x << 16);
    lav[1] = __uint_as_float((unsigned)luA.y << 16);
    lav[2] = __uint_as_float((unsigned)luA.z << 16);
    lav[3] = __uint_as_float((unsigned)luA.w << 16);
    float xrl[4] = {xrv.x, xrv.y, xrv.z, xrv.w};
    float p = 0.f;
#pragma unroll
    for (int j = 0; j < 4; ++j) {
      float ev = fmaf(we0[j], eaA.x, fmaf(we1[j], eaA.y, we2[j] * eaA.z));
      float s = lav[j] + xrl[j] + ev;
      float z = (s >= 0.f) ? s : 0.2f * s;
      p = fmaf(z, at[j], p);
    }
    p += __shfl_xor(p, 1);
    p += __shfl_xor(p, 2);
    p += __shfl_xor(p, 4);
    p += __shfl_xor(p, 8);
    const float w = __expf(p);  // |logit| << 80: no max-subtraction needed
    den += w;
    num0 = fmaf(w, lav[0], num0);
    num1 = fmaf(w, lav[1], num1);
    num2 = fmaf(w, lav[2], num2);
    num3 = fmaf(w, lav[3], num3);

    ++pos;
    luA = luB;
    eaA = eaB;
    srcB = srcC;
  }

  const float inv = 1.f / (den + 1e-16f);
  float4 r;
  r.x = num0 * inv;
  r.y = num1 * inv;
  r.z = num2 * inv;
  r.w = num3 * inv;
  // combine the 4 heads: lanes {m, m+16, m+32, m+48} hold the same channels
  r.x += __shfl_xor(r.x, 16);
  r.y += __shfl_xor(r.y, 16);
  r.z += __shfl_xor(r.z, 16);
  r.w += __shfl_xor(r.w, 16);
  r.x += __shfl_xor(r.x, 32);
  r.y += __shfl_xor(r.y, 32);
  r.z += __shfl_xor(r.z, 32);
  r.w += __shfl_xor(r.w, 32);
  if (lane < 16) {
    const int c = 4 * lane;
    float4 o;
    o.x = 0.25f * r.x + bias[c + 0];
    o.y = 0.25f * r.y + bias[c + 1];
    o.z = 0.25f * r.z + bias[c + 2];
    o.w = 0.25f * r.w + bias[c + 3];
    if (PRELU) {
      o.x = (o.x >= 0.f) ? o.x : pw[c + 0] * o.x;
      o.y = (o.y >= 0.f) ? o.y : pw[c + 1] * o.y;
      o.z = (o.z >= 0.f) ? o.z : pw[c + 2] * o.z;
      o.w = (o.w >= 0.f) ? o.w : pw[c + 3] * o.w;
    }
    ((float4*)out)[(size_t)d * 16 + lane] = o;
  }
}

extern "C" void kernel_launch(void* const* d_in, const int* in_sizes, int n_in,
                              void* d_out, int out_size, void* d_ws, size_t ws_size,
                              hipStream_t stream) {
  const float* x    = (const float*)d_in[0];
  const int*   ei   = (const int*)d_in[1];
  const float* ea   = (const float*)d_in[2];
  const float* Wl1  = (const float*)d_in[3];
  const float* Wr1  = (const float*)d_in[4];
  const float* We1  = (const float*)d_in[5];
  const float* att1 = (const float*)d_in[6];
  const float* b1   = (const float*)d_in[7];
  const float* Wl2  = (const float*)d_in[8];
  const float* Wr2  = (const float*)d_in[9];
  const float* We2  = (const float*)d_in[10];
  const float* att2 = (const float*)d_in[11];
  const float* b2   = (const float*)d_in[12];
  const float* pw   = (const float*)d_in[13];
  const int N_ = in_sizes[0] / 128;
  const int E_ = in_sizes[1] / 2;
  float* out = (float*)d_out;

  char* w = (char*)d_ws;
  auto alloc = [&](size_t bytes) {
    char* p = w;
    w += (bytes + 255) & ~size_t(255);
    return p;
  };
  ushort* xlb      = (ushort*)alloc((size_t)N_ * 256 * 2);   // bf16 gather operand
  float*  xr       = (float*)alloc((size_t)N_ * 256 * 4);
  ushort* A2       = (ushort*)alloc((size_t)N_ * 256 * 2);   // split input (covers F=128)
  float*  hbuf     = (float*)alloc((size_t)N_ * 64 * 4);
  int*    ssrc     = (int*)alloc((size_t)E_ * 4);
  float4* sea      = (float4*)alloc((size_t)E_ * 16);
  int*    deg      = (int*)alloc((size_t)N_ * 4);
  int*    rowstart = (int*)alloc((size_t)(N_ + 1) * 4);
  int*    cursor   = (int*)alloc((size_t)N_ * 4);
  int*    partial  = (int*)alloc(256 * 4);
  ushort* WT1      = (ushort*)alloc((size_t)512 * 384 * 2);
  ushort* WT2      = (ushort*)alloc((size_t)512 * 192 * 2);

  // ---- weight splits ----
  k_split_w<<<(512 * 128 + 255) / 256, 256, 0, stream>>>(Wl1, Wr1, WT1, 128);
  k_split_w<<<(512 * 64 + 255) / 256, 256, 0, stream>>>(Wl2, Wr2, WT2, 64);

  // ---- CSR build (once; shared by both layers) ----
  const int nblk = (N_ + 255) / 256;
  hipMemsetAsync(deg, 0, (size_t)N_ * 4, stream);
  k_hist<<<(E_ + 255) / 256, 256, 0, stream>>>(ei, deg, E_);
  k_scan_local<<<nblk, 256, 0, stream>>>(deg, rowstart, partial, N_);
  k_scan_partial<<<1, 256, 0, stream>>>(partial, nblk);
  k_add_off<<<nblk, 256, 0, stream>>>(rowstart, partial, N_, E_);
  hipMemcpyAsync(cursor, rowstart, (size_t)N_ * 4, hipMemcpyDeviceToDevice, stream);
  k_scatter<<<(E_ + 255) / 256, 256, 0, stream>>>(ei, ea, cursor, ssrc, sea, E_);

  const dim3 GG((N_ + 127) / 128, 4);
  const int FB = (N_ + 3) / 4;  // fused: one wave per dst node

  // ---- layer 1 ----
  k_split_x<<<(N_ * 128 / 4 + 255) / 256, 256, 0, stream>>>(x, A2, N_, 128);
  gemm_mfma<128><<<GG, 256, 0, stream>>>(A2, WT1, xlb, xr, N_);
  fused_attn<false><<<FB, 256, 0, stream>>>(xlb, xr, rowstart, ssrc, sea, We1, att1,
                                            b1, pw, hbuf, N_);
  // ---- layer 2 ----
  k_split_x<<<(N_ * 64 / 4 + 255) / 256, 256, 0, stream>>>(hbuf, A2, N_, 64);
  gemm_mfma<64><<<GG, 256, 0, stream>>>(A2, WT2, xlb, xr, N_);
  fused_attn<true><<<FB, 256, 0, stream>>>(xlb, xr, rowstart, ssrc, sea, We2, att2,
                                           b2, pw, out, N_);
}

// Round 6
// 354.580 us; speedup vs baseline: 1.1400x; 1.1400x over previous
//
#include <hip/hip_runtime.h>
#include <hip/hip_bf16.h>

#define HC 256

typedef __attribute__((ext_vector_type(8))) short bf16x8;
typedef __attribute__((ext_vector_type(4))) float f32x4;

// WT[col][3F]: col<256 from Wl, col>=256 from Wr; k-blocks hi|lo|hi
__global__ void k_split_w(const float* __restrict__ Wl, const float* __restrict__ Wr,
                          ushort* __restrict__ WT, int F) {
  int idx = blockIdx.x * blockDim.x + threadIdx.x;
  if (idx >= 512 * F) return;
  int col = idx / F, f = idx - col * F;
  float v = (col < 256) ? Wl[col * F + f] : Wr[(col - 256) * F + f];
  __hip_bfloat16 h = __float2bfloat16(v);
  __hip_bfloat16 l = __float2bfloat16(v - __bfloat162float(h));
  ushort* row = WT + (size_t)col * 3 * F;
  row[f] = *(ushort*)&h;
  row[F + f] = *(ushort*)&l;
  row[2 * F + f] = *(ushort*)&h;
}

// ======== MFMA GEMM (split fused into staging) =============================
// D = A_hi*B_hi + A_hi*B_lo + A_lo*B_hi via K-concat (Khat = 3F).
// A is read as raw fp32 (x or hbuf); hi/lo bf16 conversion happens during the
// LDS fill (lo-branch is wave-uniform per step). Block: 4 waves, 128x128 tile,
// BK=32; wave owns 32x128. xl emitted bf16 (gather operand), xr fp32.
template <int F>
__global__ __launch_bounds__(256) void gemm_mfma(const float* __restrict__ X,
                                                 const ushort* __restrict__ WT,
                                                 ushort* __restrict__ xlb,
                                                 float* __restrict__ xr, int n_nodes) {
  constexpr int KC = 3 * F;
  constexpr int NSTEP = KC / 32;
  constexpr int PITCH = 40;
  __shared__ __align__(16) ushort As[128 * PITCH];
  __shared__ __align__(16) ushort Bs[128 * PITCH];
  const int tid = threadIdx.x;
  const int wv = tid >> 6, lane = tid & 63;
  const int m16 = lane & 15, quad = lane >> 4;
  const int row0 = blockIdx.x * 128;
  const int col0 = blockIdx.y * 128;

  f32x4 acc[2][8];
#pragma unroll
  for (int i = 0; i < 2; ++i)
#pragma unroll
    for (int j = 0; j < 8; ++j) acc[i][j] = (f32x4){0.f, 0.f, 0.f, 0.f};

  for (int s = 0; s < NSTEP; ++s) {
    const int khat = s * 32;
    const bool lo = (khat >= 2 * F);
    const int c0 = (khat < F) ? khat : (lo ? khat - 2 * F : khat - F);
    __syncthreads();
#pragma unroll
    for (int c = 0; c < 2; ++c) {
      int u = tid + 256 * c;  // 512 16B-chunks per tile
      int r = u >> 2, ch = u & 3;
      int grow = row0 + r;
      float4 v0 = {0.f, 0.f, 0.f, 0.f}, v1 = {0.f, 0.f, 0.f, 0.f};
      if (grow < n_nodes) {
        const float* xp = X + (size_t)grow * F + c0 + ch * 8;
        v0 = *(const float4*)xp;
        v1 = *(const float4*)(xp + 4);
      }
      float vv[8] = {v0.x, v0.y, v0.z, v0.w, v1.x, v1.y, v1.z, v1.w};
      __align__(16) ushort hb[8];
      if (lo) {
#pragma unroll
        for (int i = 0; i < 8; ++i) {
          __hip_bfloat16 h = __float2bfloat16(vv[i]);
          __hip_bfloat16 l = __float2bfloat16(vv[i] - __bfloat162float(h));
          hb[i] = *(ushort*)&l;
        }
      } else {
#pragma unroll
        for (int i = 0; i < 8; ++i) {
          __hip_bfloat16 h = __float2bfloat16(vv[i]);
          hb[i] = *(ushort*)&h;
        }
      }
      *(int4*)&As[r * PITCH + ch * 8] = *(int4*)hb;
      int4 bval = *(const int4*)(WT + (size_t)(col0 + r) * KC + khat + ch * 8);
      *(int4*)&Bs[r * PITCH + ch * 8] = bval;
    }
    __syncthreads();
    bf16x8 af[2];
#pragma unroll
    for (int i = 0; i < 2; ++i)
      af[i] = *(bf16x8*)&As[(wv * 32 + i * 16 + m16) * PITCH + quad * 8];
#pragma unroll
    for (int j = 0; j < 8; ++j) {
      bf16x8 bf = *(bf16x8*)&Bs[(j * 16 + m16) * PITCH + quad * 8];
      acc[0][j] = __builtin_amdgcn_mfma_f32_16x16x32_bf16(af[0], bf, acc[0][j], 0, 0, 0);
      acc[1][j] = __builtin_amdgcn_mfma_f32_16x16x32_bf16(af[1], bf, acc[1][j], 0, 0, 0);
    }
  }
  // epilogue: C/D layout col=lane&15, row=quad*4+reg
  const bool is_xl = (col0 < 256);
#pragma unroll
  for (int i = 0; i < 2; ++i) {
#pragma unroll
    for (int r = 0; r < 4; ++r) {
      int grow = row0 + wv * 32 + i * 16 + quad * 4 + r;
      if (grow < n_nodes) {
#pragma unroll
        for (int j = 0; j < 8; ++j) {
          float v = acc[i][j][r];
          int col = col0 + j * 16 + m16;
          if (is_xl) {
            __hip_bfloat16 h = __float2bfloat16(v);
            xlb[(size_t)grow * 256 + col] = *(ushort*)&h;
          } else {
            xr[(size_t)grow * 256 + (col - 256)] = v;
          }
        }
      }
    }
  }
}

// ================= CSR build (edges bucketed by dst) =======================
__global__ void k_hist(const int* __restrict__ ei, int* __restrict__ deg, int E_) {
  int e = blockIdx.x * blockDim.x + threadIdx.x;
  if (e < E_) atomicAdd(&deg[ei[E_ + e]], 1);
}

__global__ void k_scan_local(const int* __restrict__ deg, int* __restrict__ rowstart,
                             int* __restrict__ partial, int n) {
  __shared__ int a[256], b[256];
  const int t = threadIdx.x;
  const int i = blockIdx.x * 256 + t;
  const int v = (i < n) ? deg[i] : 0;
  a[t] = v;
  __syncthreads();
  int* cur = a;
  int* nxt = b;
  for (int off = 1; off < 256; off <<= 1) {
    int x = cur[t];
    if (t >= off) x += cur[t - off];
    nxt[t] = x;
    __syncthreads();
    int* tmp = cur; cur = nxt; nxt = tmp;
  }
  const int incl = cur[t];
  if (i < n) rowstart[i] = incl - v;
  if (t == 255) partial[blockIdx.x] = incl;
}

__global__ void k_scan_partial(int* __restrict__ partial, int nblk) {
  __shared__ int a[256], b[256];
  const int t = threadIdx.x;
  const int v = (t < nblk) ? partial[t] : 0;
  a[t] = v;
  __syncthreads();
  int* cur = a;
  int* nxt = b;
  for (int off = 1; off < 256; off <<= 1) {
    int x = cur[t];
    if (t >= off) x += cur[t - off];
    nxt[t] = x;
    __syncthreads();
    int* tmp = cur; cur = nxt; nxt = tmp;
  }
  if (t < nblk) partial[t] = cur[t] - v;
}

__global__ void k_add_off(int* __restrict__ rowstart, const int* __restrict__ partial,
                          int n, int E_) {
  int i = blockIdx.x * blockDim.x + threadIdx.x;
  if (i < n) rowstart[i] += partial[i >> 8];
  if (i == 0) rowstart[n] = E_;
}

__global__ void k_scatter(const int* __restrict__ ei, const float* __restrict__ ea,
                          int* __restrict__ cursor, int* __restrict__ ssrc,
                          float4* __restrict__ sea, int E_) {
  int e = blockIdx.x * blockDim.x + threadIdx.x;
  if (e < E_) {
    int dst = ei[E_ + e];
    int pos = atomicAdd(&cursor[dst], 1);
    ssrc[pos] = ei[e];
    sea[pos] = make_float4(ea[e * 3], ea[e * 3 + 1], ea[e * 3 + 2], 0.f);
  }
}

// ================= fused per-destination attention =========================
// One wave per dst node (d forced wave-uniform -> scalar CSR/sea loads).
// 2-edge unroll, clamped branch-free prefetch: 2 row gathers in flight, src
// indices prefetched a full pair ahead. Online softmax, no atomics.
__device__ __forceinline__ void edge_step(
    const ushort4& lu, const float4& eav, const float* we0, const float* we1,
    const float* we2, const float* at, const float* xrl, float& num0, float& num1,
    float& num2, float& num3, float& den) {
  float lav[4];
  lav[0] = __uint_as_float((unsigned)lu.x << 16);
  lav[1] = __uint_as_float((unsigned)lu.y << 16);
  lav[2] = __uint_as_float((unsigned)lu.z << 16);
  lav[3] = __uint_as_float((unsigned)lu.w << 16);
  float p = 0.f;
#pragma unroll
  for (int j = 0; j < 4; ++j) {
    float ev = fmaf(we0[j], eav.x, fmaf(we1[j], eav.y, we2[j] * eav.z));
    float s = lav[j] + xrl[j] + ev;
    float z = (s >= 0.f) ? s : 0.2f * s;
    p = fmaf(z, at[j], p);
  }
  p += __shfl_xor(p, 1);
  p += __shfl_xor(p, 2);
  p += __shfl_xor(p, 4);
  p += __shfl_xor(p, 8);
  const float w = __expf(p);  // |logit| << 80: no max-subtraction needed
  den += w;
  num0 = fmaf(w, lav[0], num0);
  num1 = fmaf(w, lav[1], num1);
  num2 = fmaf(w, lav[2], num2);
  num3 = fmaf(w, lav[3], num3);
}

template <bool PRELU>
__global__ __launch_bounds__(256) void fused_attn(
    const ushort* __restrict__ xlb, const float* __restrict__ xr,
    const int* __restrict__ rowstart, const int* __restrict__ ssrc,
    const float4* __restrict__ sea, const float* __restrict__ We,
    const float* __restrict__ att, const float* __restrict__ bias,
    const float* __restrict__ pw, float* __restrict__ out, int n) {
  const int lane = threadIdx.x & 63;
  const int d =
      __builtin_amdgcn_readfirstlane((blockIdx.x * blockDim.x + threadIdx.x) >> 6);
  if (d >= n) return;
  float we0[4], we1[4], we2[4], at[4];
#pragma unroll
  for (int j = 0; j < 4; ++j) {
    int r = 4 * lane + j;
    we0[j] = We[r * 3 + 0];
    we1[j] = We[r * 3 + 1];
    we2[j] = We[r * 3 + 2];
    at[j] = att[r];
  }
  const ushort4* xlb4 = (const ushort4*)xlb;
  const float4 xrv = ((const float4*)xr)[(size_t)d * 64 + lane];
  float xrl[4] = {xrv.x, xrv.y, xrv.z, xrv.w};

  int pos = rowstart[d];
  const int end = rowstart[d + 1];
  float num0 = 0.f, num1 = 0.f, num2 = 0.f, num3 = 0.f, den = 0.f;

  if (pos < end) {
    const int last = end - 1;
    const int p1 = min(pos + 1, last);
    int s0 = ssrc[pos], s1 = ssrc[p1];
    ushort4 g0 = xlb4[(size_t)s0 * 64 + lane];
    ushort4 g1 = xlb4[(size_t)s1 * 64 + lane];
    float4 e0 = sea[pos], e1 = sea[p1];
    int sn0 = ssrc[min(pos + 2, last)];
    int sn1 = ssrc[min(pos + 3, last)];

    while (pos + 2 <= end) {
      const int p2 = min(pos + 2, last), p3 = min(pos + 3, last);
      ushort4 h0 = xlb4[(size_t)sn0 * 64 + lane];
      ushort4 h1 = xlb4[(size_t)sn1 * 64 + lane];
      float4 f0 = sea[p2], f1 = sea[p3];
      sn0 = ssrc[min(pos + 4, last)];
      sn1 = ssrc[min(pos + 5, last)];
      edge_step(g0, e0, we0, we1, we2, at, xrl, num0, num1, num2, num3, den);
      edge_step(g1, e1, we0, we1, we2, at, xrl, num0, num1, num2, num3, den);
      g0 = h0; g1 = h1; e0 = f0; e1 = f1;
      pos += 2;
    }
    if (pos < end)
      edge_step(g0, e0, we0, we1, we2, at, xrl, num0, num1, num2, num3, den);
  }

  const float inv = 1.f / (den + 1e-16f);
  float4 r;
  r.x = num0 * inv;
  r.y = num1 * inv;
  r.z = num2 * inv;
  r.w = num3 * inv;
  // combine the 4 heads: lanes {m, m+16, m+32, m+48} hold the same channels
  r.x += __shfl_xor(r.x, 16);
  r.y += __shfl_xor(r.y, 16);
  r.z += __shfl_xor(r.z, 16);
  r.w += __shfl_xor(r.w, 16);
  r.x += __shfl_xor(r.x, 32);
  r.y += __shfl_xor(r.y, 32);
  r.z += __shfl_xor(r.z, 32);
  r.w += __shfl_xor(r.w, 32);
  if (lane < 16) {
    const int c = 4 * lane;
    float4 o;
    o.x = 0.25f * r.x + bias[c + 0];
    o.y = 0.25f * r.y + bias[c + 1];
    o.z = 0.25f * r.z + bias[c + 2];
    o.w = 0.25f * r.w + bias[c + 3];
    if (PRELU) {
      o.x = (o.x >= 0.f) ? o.x : pw[c + 0] * o.x;
      o.y = (o.y >= 0.f) ? o.y : pw[c + 1] * o.y;
      o.z = (o.z >= 0.f) ? o.z : pw[c + 2] * o.z;
      o.w = (o.w >= 0.f) ? o.w : pw[c + 3] * o.w;
    }
    ((float4*)out)[(size_t)d * 16 + lane] = o;
  }
}

extern "C" void kernel_launch(void* const* d_in, const int* in_sizes, int n_in,
                              void* d_out, int out_size, void* d_ws, size_t ws_size,
                              hipStream_t stream) {
  const float* x    = (const float*)d_in[0];
  const int*   ei   = (const int*)d_in[1];
  const float* ea   = (const float*)d_in[2];
  const float* Wl1  = (const float*)d_in[3];
  const float* Wr1  = (const float*)d_in[4];
  const float* We1  = (const float*)d_in[5];
  const float* att1 = (const float*)d_in[6];
  const float* b1   = (const float*)d_in[7];
  const float* Wl2  = (const float*)d_in[8];
  const float* Wr2  = (const float*)d_in[9];
  const float* We2  = (const float*)d_in[10];
  const float* att2 = (const float*)d_in[11];
  const float* b2   = (const float*)d_in[12];
  const float* pw   = (const float*)d_in[13];
  const int N_ = in_sizes[0] / 128;
  const int E_ = in_sizes[1] / 2;
  float* out = (float*)d_out;

  char* w = (char*)d_ws;
  auto alloc = [&](size_t bytes) {
    char* p = w;
    w += (bytes + 255) & ~size_t(255);
    return p;
  };
  ushort* xlb      = (ushort*)alloc((size_t)N_ * 256 * 2);   // bf16 gather operand
  float*  xr       = (float*)alloc((size_t)N_ * 256 * 4);
  float*  hbuf     = (float*)alloc((size_t)N_ * 64 * 4);
  int*    ssrc     = (int*)alloc((size_t)E_ * 4);
  float4* sea      = (float4*)alloc((size_t)E_ * 16);
  int*    deg      = (int*)alloc((size_t)N_ * 4);
  int*    rowstart = (int*)alloc((size_t)(N_ + 1) * 4);
  int*    cursor   = (int*)alloc((size_t)N_ * 4);
  int*    partial  = (int*)alloc(256 * 4);
  ushort* WT1      = (ushort*)alloc((size_t)512 * 384 * 2);
  ushort* WT2      = (ushort*)alloc((size_t)512 * 192 * 2);

  // ---- weight splits ----
  k_split_w<<<(512 * 128 + 255) / 256, 256, 0, stream>>>(Wl1, Wr1, WT1, 128);
  k_split_w<<<(512 * 64 + 255) / 256, 256, 0, stream>>>(Wl2, Wr2, WT2, 64);

  // ---- CSR build (once; shared by both layers) ----
  const int nblk = (N_ + 255) / 256;
  hipMemsetAsync(deg, 0, (size_t)N_ * 4, stream);
  k_hist<<<(E_ + 255) / 256, 256, 0, stream>>>(ei, deg, E_);
  k_scan_local<<<nblk, 256, 0, stream>>>(deg, rowstart, partial, N_);
  k_scan_partial<<<1, 256, 0, stream>>>(partial, nblk);
  k_add_off<<<nblk, 256, 0, stream>>>(rowstart, partial, N_, E_);
  hipMemcpyAsync(cursor, rowstart, (size_t)N_ * 4, hipMemcpyDeviceToDevice, stream);
  k_scatter<<<(E_ + 255) / 256, 256, 0, stream>>>(ei, ea, cursor, ssrc, sea, E_);

  const dim3 GG((N_ + 127) / 128, 4);
  const int FB = (N_ + 3) / 4;  // fused: one wave per dst node

  // ---- layer 1 ----
  gemm_mfma<128><<<GG, 256, 0, stream>>>(x, WT1, xlb, xr, N_);
  fused_attn<false><<<FB, 256, 0, stream>>>(xlb, xr, rowstart, ssrc, sea, We1, att1,
                                            b1, pw, hbuf, N_);
  // ---- layer 2 ----
  gemm_mfma<64><<<GG, 256, 0, stream>>>(hbuf, WT2, xlb, xr, N_);
  fused_attn<true><<<FB, 256, 0, stream>>>(xlb, xr, rowstart, ssrc, sea, We2, att2,
                                           b2, pw, out, N_);
}

// Round 7
// 335.001 us; speedup vs baseline: 1.2066x; 1.0584x over previous
//
#include <hip/hip_runtime.h>
#include <hip/hip_bf16.h>

#define HC 256

typedef __attribute__((ext_vector_type(8))) short bf16x8;
typedef __attribute__((ext_vector_type(4))) float f32x4;

__device__ __forceinline__ void gl_lds16(const void* g, void* l) {
  __builtin_amdgcn_global_load_lds(
      (const __attribute__((address_space(1))) unsigned int*)g,
      (__attribute__((address_space(3))) unsigned int*)l, 16, 0, 0);
}

// ======== split fp32 -> (hi|lo) bf16: A2[row][2F] = [hi(F) | lo(F)] ========
__global__ void k_split_x(const float* __restrict__ x, ushort* __restrict__ A2,
                          int n, int F) {
  int idx = blockIdx.x * blockDim.x + threadIdx.x;  // one per 4 elements
  int total = n * F / 4;
  if (idx >= total) return;
  int fq = F / 4;
  int row = idx / fq, q = idx - row * fq;
  float4 v = ((const float4*)x)[idx];
  float vv[4] = {v.x, v.y, v.z, v.w};
  ushort hb[4], lb[4];
#pragma unroll
  for (int j = 0; j < 4; ++j) {
    __hip_bfloat16 h = __float2bfloat16(vv[j]);
    hb[j] = *(ushort*)&h;
    __hip_bfloat16 l = __float2bfloat16(vv[j] - __bfloat162float(h));
    lb[j] = *(ushort*)&l;
  }
  ushort* rp = A2 + (size_t)row * 2 * F;
  *(ushort4*)(rp + q * 4) = make_ushort4(hb[0], hb[1], hb[2], hb[3]);
  *(ushort4*)(rp + F + q * 4) = make_ushort4(lb[0], lb[1], lb[2], lb[3]);
}

// WT[col][3F]: col<256 from Wl, col>=256 from Wr; k-blocks hi|lo|hi
__global__ void k_split_w(const float* __restrict__ Wl, const float* __restrict__ Wr,
                          ushort* __restrict__ WT, int F) {
  int idx = blockIdx.x * blockDim.x + threadIdx.x;
  if (idx >= 512 * F) return;
  int col = idx / F, f = idx - col * F;
  float v = (col < 256) ? Wl[col * F + f] : Wr[(col - 256) * F + f];
  __hip_bfloat16 h = __float2bfloat16(v);
  __hip_bfloat16 l = __float2bfloat16(v - __bfloat162float(h));
  ushort* row = WT + (size_t)col * 3 * F;
  row[f] = *(ushort*)&h;
  row[F + f] = *(ushort*)&l;
  row[2 * F + f] = *(ushort*)&h;
}

// ======== MFMA GEMM (m97-style: global_load_lds + XOR-swizzled LDS) ========
// D = A_hi*B_hi + A_hi*B_lo + A_lo*B_hi via K-concat (Khat = 3F).
// 4 waves, block tile 128M x 128N, wave tile 64x64, BK=64 khat.
// LDS linear [128 rows][8 chunks of 16B]; chunk stored at slot c^(row&7)
// (swizzle applied on the per-lane GLOBAL address; LDS dst stays linear in
// lane as global_load_lds requires). Frag ds_read_b128 then lands 2-way max.
template <int F>
__global__ __launch_bounds__(256) void gemm_mfma(const ushort* __restrict__ A2,
                                                 const ushort* __restrict__ WT,
                                                 ushort* __restrict__ xlb,
                                                 float* __restrict__ xr, int n_nodes) {
  constexpr int KC = 3 * F;
  constexpr int NSTEP = KC / 64;
  __shared__ __align__(16) ushort As[128 * 64];
  __shared__ __align__(16) ushort Bs[128 * 64];
  const int tid = threadIdx.x;
  const int wv = tid >> 6, lane = tid & 63;
  const int m16 = lane & 15, quad = lane >> 4;
  const int col0 = blockIdx.x * 128;   // 0..3 -> xl cols then xr cols
  const int row0 = blockIdx.y * 128;
  const int wm = (wv >> 1) * 64, wn = (wv & 1) * 64;

  f32x4 acc[4][4];
#pragma unroll
  for (int i = 0; i < 4; ++i)
#pragma unroll
    for (int j = 0; j < 4; ++j) acc[i][j] = (f32x4){0.f, 0.f, 0.f, 0.f};

  for (int s = 0; s < NSTEP; ++s) {
    const int khat = s * 64;
    const int asrc = (khat < F) ? khat : khat - F;  // hi|hi|lo within A2 row
    __syncthreads();
#pragma unroll
    for (int t = 0; t < 4; ++t) {
      const int sl16 = tid + 256 * t;       // LDS slot index (16B units), linear in lane
      const int row = sl16 >> 3, sl = sl16 & 7;
      const int gch = sl ^ (row & 7);       // which global chunk lives in this slot
      const int grow = row0 + row;
      if (grow < n_nodes)
        gl_lds16(A2 + (size_t)grow * (2 * F) + asrc + gch * 8, As + sl16 * 8);
      gl_lds16(WT + (size_t)(col0 + row) * KC + khat + gch * 8, Bs + sl16 * 8);
    }
    __syncthreads();
#pragma unroll
    for (int kh = 0; kh < 2; ++kh) {
      bf16x8 af[4], bf[4];
#pragma unroll
      for (int i = 0; i < 4; ++i) {
        const int row = wm + i * 16 + m16;
        const int slot = (kh * 4 + quad) ^ (row & 7);
        af[i] = *(bf16x8*)&As[row * 64 + slot * 8];
      }
#pragma unroll
      for (int j = 0; j < 4; ++j) {
        const int col = wn + j * 16 + m16;
        const int slot = (kh * 4 + quad) ^ (col & 7);
        bf[j] = *(bf16x8*)&Bs[col * 64 + slot * 8];
      }
#pragma unroll
      for (int i = 0; i < 4; ++i)
#pragma unroll
        for (int j = 0; j < 4; ++j)
          acc[i][j] =
              __builtin_amdgcn_mfma_f32_16x16x32_bf16(af[i], bf[j], acc[i][j], 0, 0, 0);
    }
  }
  // epilogue: C/D layout col=lane&15, row=quad*4+reg
  const bool is_xl = (col0 < 256);
#pragma unroll
  for (int i = 0; i < 4; ++i) {
#pragma unroll
    for (int r = 0; r < 4; ++r) {
      const int grow = row0 + wm + i * 16 + quad * 4 + r;
      if (grow < n_nodes) {
#pragma unroll
        for (int j = 0; j < 4; ++j) {
          const float v = acc[i][j][r];
          const int col = col0 + wn + j * 16 + m16;
          if (is_xl) {
            __hip_bfloat16 h = __float2bfloat16(v);
            xlb[(size_t)grow * 256 + col] = *(ushort*)&h;
          } else {
            xr[(size_t)grow * 256 + (col - 256)] = v;
          }
        }
      }
    }
  }
}

// ================= CSR build (edges bucketed by dst) =======================
__global__ void k_hist(const int* __restrict__ ei, int* __restrict__ deg, int E_) {
  int e = blockIdx.x * blockDim.x + threadIdx.x;
  if (e < E_) atomicAdd(&deg[ei[E_ + e]], 1);
}

__global__ void k_scan_local(const int* __restrict__ deg, int* __restrict__ rowstart,
                             int* __restrict__ partial, int n) {
  __shared__ int a[256], b[256];
  const int t = threadIdx.x;
  const int i = blockIdx.x * 256 + t;
  const int v = (i < n) ? deg[i] : 0;
  a[t] = v;
  __syncthreads();
  int* cur = a;
  int* nxt = b;
  for (int off = 1; off < 256; off <<= 1) {
    int x = cur[t];
    if (t >= off) x += cur[t - off];
    nxt[t] = x;
    __syncthreads();
    int* tmp = cur; cur = nxt; nxt = tmp;
  }
  const int incl = cur[t];
  if (i < n) rowstart[i] = incl - v;
  if (t == 255) partial[blockIdx.x] = incl;
}

__global__ void k_scan_partial(int* __restrict__ partial, int nblk) {
  __shared__ int a[256], b[256];
  const int t = threadIdx.x;
  const int v = (t < nblk) ? partial[t] : 0;
  a[t] = v;
  __syncthreads();
  int* cur = a;
  int* nxt = b;
  for (int off = 1; off < 256; off <<= 1) {
    int x = cur[t];
    if (t >= off) x += cur[t - off];
    nxt[t] = x;
    __syncthreads();
    int* tmp = cur; cur = nxt; nxt = tmp;
  }
  if (t < nblk) partial[t] = cur[t] - v;
}

__global__ void k_add_off(int* __restrict__ rowstart, const int* __restrict__ partial,
                          int n, int E_) {
  int i = blockIdx.x * blockDim.x + threadIdx.x;
  if (i < n) rowstart[i] += partial[i >> 8];
  if (i == 0) rowstart[n] = E_;
}

__global__ void k_scatter(const int* __restrict__ ei, const float* __restrict__ ea,
                          int* __restrict__ cursor, int* __restrict__ ssrc,
                          float4* __restrict__ sea, int E_) {
  int e = blockIdx.x * blockDim.x + threadIdx.x;
  if (e < E_) {
    int dst = ei[E_ + e];
    int pos = atomicAdd(&cursor[dst], 1);
    ssrc[pos] = ei[e];
    sea[pos] = make_float4(ea[e * 3], ea[e * 3 + 1], ea[e * 3 + 2], 0.f);
  }
}

// ================= fused per-destination attention =========================
// One wave per dst node (d wave-uniform -> scalar CSR/sea loads). 2-edge
// unroll with clamped branch-free prefetch. MODE 0: write hi|lo bf16 split
// (feeds next layer's GEMM directly). MODE 1: write fp32 + PReLU (final).
__device__ __forceinline__ void edge_step(
    const ushort4& lu, const float4& eav, const float* we0, const float* we1,
    const float* we2, const float* at, const float* xrl, float& num0, float& num1,
    float& num2, float& num3, float& den) {
  float lav[4];
  lav[0] = __uint_as_float((unsigned)lu.x << 16);
  lav[1] = __uint_as_float((unsigned)lu.y << 16);
  lav[2] = __uint_as_float((unsigned)lu.z << 16);
  lav[3] = __uint_as_float((unsigned)lu.w << 16);
  float p = 0.f;
#pragma unroll
  for (int j = 0; j < 4; ++j) {
    float ev = fmaf(we0[j], eav.x, fmaf(we1[j], eav.y, we2[j] * eav.z));
    float s = lav[j] + xrl[j] + ev;
    float z = (s >= 0.f) ? s : 0.2f * s;
    p = fmaf(z, at[j], p);
  }
  p += __shfl_xor(p, 1);
  p += __shfl_xor(p, 2);
  p += __shfl_xor(p, 4);
  p += __shfl_xor(p, 8);
  const float w = __expf(p);  // |logit| << 80: no max-subtraction needed
  den += w;
  num0 = fmaf(w, lav[0], num0);
  num1 = fmaf(w, lav[1], num1);
  num2 = fmaf(w, lav[2], num2);
  num3 = fmaf(w, lav[3], num3);
}

template <int MODE>
__global__ __launch_bounds__(256) void fused_attn(
    const ushort* __restrict__ xlb, const float* __restrict__ xr,
    const int* __restrict__ rowstart, const int* __restrict__ ssrc,
    const float4* __restrict__ sea, const float* __restrict__ We,
    const float* __restrict__ att, const float* __restrict__ bias,
    const float* __restrict__ pw, float* __restrict__ out,
    ushort* __restrict__ outs, int n) {
  const int lane = threadIdx.x & 63;
  const int d =
      __builtin_amdgcn_readfirstlane((blockIdx.x * blockDim.x + threadIdx.x) >> 6);
  if (d >= n) return;
  float we0[4], we1[4], we2[4], at[4];
#pragma unroll
  for (int j = 0; j < 4; ++j) {
    int r = 4 * lane + j;
    we0[j] = We[r * 3 + 0];
    we1[j] = We[r * 3 + 1];
    we2[j] = We[r * 3 + 2];
    at[j] = att[r];
  }
  const ushort4* xlb4 = (const ushort4*)xlb;
  const float4 xrv = ((const float4*)xr)[(size_t)d * 64 + lane];
  float xrl[4] = {xrv.x, xrv.y, xrv.z, xrv.w};

  int pos = rowstart[d];
  const int end = rowstart[d + 1];
  float num0 = 0.f, num1 = 0.f, num2 = 0.f, num3 = 0.f, den = 0.f;

  if (pos < end) {
    const int last = end - 1;
    const int p1 = min(pos + 1, last);
    int s0 = ssrc[pos], s1 = ssrc[p1];
    ushort4 g0 = xlb4[(size_t)s0 * 64 + lane];
    ushort4 g1 = xlb4[(size_t)s1 * 64 + lane];
    float4 e0 = sea[pos], e1 = sea[p1];
    int sn0 = ssrc[min(pos + 2, last)];
    int sn1 = ssrc[min(pos + 3, last)];

    while (pos + 2 <= end) {
      const int p2 = min(pos + 2, last), p3 = min(pos + 3, last);
      ushort4 h0 = xlb4[(size_t)sn0 * 64 + lane];
      ushort4 h1 = xlb4[(size_t)sn1 * 64 + lane];
      float4 f0 = sea[p2], f1 = sea[p3];
      sn0 = ssrc[min(pos + 4, last)];
      sn1 = ssrc[min(pos + 5, last)];
      edge_step(g0, e0, we0, we1, we2, at, xrl, num0, num1, num2, num3, den);
      edge_step(g1, e1, we0, we1, we2, at, xrl, num0, num1, num2, num3, den);
      g0 = h0; g1 = h1; e0 = f0; e1 = f1;
      pos += 2;
    }
    if (pos < end)
      edge_step(g0, e0, we0, we1, we2, at, xrl, num0, num1, num2, num3, den);
  }

  const float inv = 1.f / (den + 1e-16f);
  float4 r;
  r.x = num0 * inv;
  r.y = num1 * inv;
  r.z = num2 * inv;
  r.w = num3 * inv;
  // combine the 4 heads: lanes {m, m+16, m+32, m+48} hold the same channels
  r.x += __shfl_xor(r.x, 16);
  r.y += __shfl_xor(r.y, 16);
  r.z += __shfl_xor(r.z, 16);
  r.w += __shfl_xor(r.w, 16);
  r.x += __shfl_xor(r.x, 32);
  r.y += __shfl_xor(r.y, 32);
  r.z += __shfl_xor(r.z, 32);
  r.w += __shfl_xor(r.w, 32);
  if (lane < 16) {
    const int c = 4 * lane;
    float o[4];
    o[0] = 0.25f * r.x + bias[c + 0];
    o[1] = 0.25f * r.y + bias[c + 1];
    o[2] = 0.25f * r.z + bias[c + 2];
    o[3] = 0.25f * r.w + bias[c + 3];
    if (MODE == 1) {
#pragma unroll
      for (int j = 0; j < 4; ++j) o[j] = (o[j] >= 0.f) ? o[j] : pw[c + j] * o[j];
      ((float4*)out)[(size_t)d * 16 + lane] =
          make_float4(o[0], o[1], o[2], o[3]);
    } else {
      // emit hi|lo bf16 split for next layer's GEMM: outs[d][128] = [hi64|lo64]
      ushort hb[4], lb[4];
#pragma unroll
      for (int j = 0; j < 4; ++j) {
        __hip_bfloat16 h = __float2bfloat16(o[j]);
        hb[j] = *(ushort*)&h;
        __hip_bfloat16 l = __float2bfloat16(o[j] - __bfloat162float(h));
        lb[j] = *(ushort*)&l;
      }
      *(ushort4*)(outs + (size_t)d * 128 + c) = make_ushort4(hb[0], hb[1], hb[2], hb[3]);
      *(ushort4*)(outs + (size_t)d * 128 + 64 + c) =
          make_ushort4(lb[0], lb[1], lb[2], lb[3]);
    }
  }
}

extern "C" void kernel_launch(void* const* d_in, const int* in_sizes, int n_in,
                              void* d_out, int out_size, void* d_ws, size_t ws_size,
                              hipStream_t stream) {
  const float* x    = (const float*)d_in[0];
  const int*   ei   = (const int*)d_in[1];
  const float* ea   = (const float*)d_in[2];
  const float* Wl1  = (const float*)d_in[3];
  const float* Wr1  = (const float*)d_in[4];
  const float* We1  = (const float*)d_in[5];
  const float* att1 = (const float*)d_in[6];
  const float* b1   = (const float*)d_in[7];
  const float* Wl2  = (const float*)d_in[8];
  const float* Wr2  = (const float*)d_in[9];
  const float* We2  = (const float*)d_in[10];
  const float* att2 = (const float*)d_in[11];
  const float* b2   = (const float*)d_in[12];
  const float* pw   = (const float*)d_in[13];
  const int N_ = in_sizes[0] / 128;
  const int E_ = in_sizes[1] / 2;
  float* out = (float*)d_out;

  char* w = (char*)d_ws;
  auto alloc = [&](size_t bytes) {
    char* p = w;
    w += (bytes + 255) & ~size_t(255);
    return p;
  };
  ushort* xlb      = (ushort*)alloc((size_t)N_ * 256 * 2);   // bf16 gather operand
  float*  xr       = (float*)alloc((size_t)N_ * 256 * 4);
  ushort* A2x      = (ushort*)alloc((size_t)N_ * 256 * 2);   // split of x (F=128)
  ushort* h2       = (ushort*)alloc((size_t)N_ * 128 * 2);   // split of h (F=64)
  int*    ssrc     = (int*)alloc((size_t)E_ * 4);
  float4* sea      = (float4*)alloc((size_t)E_ * 16);
  int*    deg      = (int*)alloc((size_t)N_ * 4);
  int*    rowstart = (int*)alloc((size_t)(N_ + 1) * 4);
  int*    cursor   = (int*)alloc((size_t)N_ * 4);
  int*    partial  = (int*)alloc(256 * 4);
  ushort* WT1      = (ushort*)alloc((size_t)512 * 384 * 2);
  ushort* WT2      = (ushort*)alloc((size_t)512 * 192 * 2);

  // ---- weight splits ----
  k_split_w<<<(512 * 128 + 255) / 256, 256, 0, stream>>>(Wl1, Wr1, WT1, 128);
  k_split_w<<<(512 * 64 + 255) / 256, 256, 0, stream>>>(Wl2, Wr2, WT2, 64);

  // ---- CSR build (once; shared by both layers) ----
  const int nblk = (N_ + 255) / 256;
  hipMemsetAsync(deg, 0, (size_t)N_ * 4, stream);
  k_hist<<<(E_ + 255) / 256, 256, 0, stream>>>(ei, deg, E_);
  k_scan_local<<<nblk, 256, 0, stream>>>(deg, rowstart, partial, N_);
  k_scan_partial<<<1, 256, 0, stream>>>(partial, nblk);
  k_add_off<<<nblk, 256, 0, stream>>>(rowstart, partial, N_, E_);
  hipMemcpyAsync(cursor, rowstart, (size_t)N_ * 4, hipMemcpyDeviceToDevice, stream);
  k_scatter<<<(E_ + 255) / 256, 256, 0, stream>>>(ei, ea, cursor, ssrc, sea, E_);

  const dim3 GG(4, (N_ + 127) / 128);  // x = col-block (xl,xl,xr,xr), y = rows
  const int FB = (N_ + 3) / 4;         // fused: one wave per dst node

  // ---- layer 1 ----
  k_split_x<<<(N_ * 128 / 4 + 255) / 256, 256, 0, stream>>>(x, A2x, N_, 128);
  gemm_mfma<128><<<GG, 256, 0, stream>>>(A2x, WT1, xlb, xr, N_);
  fused_attn<0><<<FB, 256, 0, stream>>>(xlb, xr, rowstart, ssrc, sea, We1, att1,
                                        b1, pw, nullptr, h2, N_);
  // ---- layer 2 ----
  gemm_mfma<64><<<GG, 256, 0, stream>>>(h2, WT2, xlb, xr, N_);
  fused_attn<1><<<FB, 256, 0, stream>>>(xlb, xr, rowstart, ssrc, sea, We2, att2,
                                        b2, pw, out, nullptr, N_);
}

// Round 8
// 301.763 us; speedup vs baseline: 1.3395x; 1.1101x over previous
//
#include <hip/hip_runtime.h>
#include <hip/hip_bf16.h>

#define HC 256

typedef __attribute__((ext_vector_type(8))) short bf16x8;
typedef __attribute__((ext_vector_type(4))) float f32x4;
typedef __attribute__((ext_vector_type(2))) float f32x2;

__device__ __forceinline__ void gl_lds16(const void* g, void* l) {
  __builtin_amdgcn_global_load_lds(
      (const __attribute__((address_space(1))) unsigned int*)g,
      (__attribute__((address_space(3))) unsigned int*)l, 16, 0, 0);
}

// ==== weight splits for BOTH layers + deg zeroing, one kernel ==============
// WT[col][3F]: col<256 from Wl, col>=256 from Wr; k-blocks hi|lo|hi
__device__ __forceinline__ void split_w_one(const float* Wl, const float* Wr,
                                            ushort* WT, int F, int idx) {
  int col = idx / F, f = idx - col * F;
  float v = (col < 256) ? Wl[col * F + f] : Wr[(col - 256) * F + f];
  __hip_bfloat16 h = __float2bfloat16(v);
  __hip_bfloat16 l = __float2bfloat16(v - __bfloat162float(h));
  ushort* row = WT + (size_t)col * 3 * F;
  row[f] = *(ushort*)&h;
  row[F + f] = *(ushort*)&l;
  row[2 * F + f] = *(ushort*)&h;
}

__global__ void k_weights_deg(const float* __restrict__ Wl1, const float* __restrict__ Wr1,
                              ushort* __restrict__ WT1, const float* __restrict__ Wl2,
                              const float* __restrict__ Wr2, ushort* __restrict__ WT2,
                              int* __restrict__ deg, int n) {
  int idx = blockIdx.x * blockDim.x + threadIdx.x;
  const int t1 = 512 * 128, t2 = 512 * 64;
  if (idx < t1) {
    split_w_one(Wl1, Wr1, WT1, 128, idx);
  } else if (idx < t1 + t2) {
    split_w_one(Wl2, Wr2, WT2, 64, idx - t1);
  } else if (idx < t1 + t2 + n) {
    deg[idx - t1 - t2] = 0;
  }
}

// ======== MFMA GEMM (global_load_lds + XOR-swizzled LDS) ===================
// col-blocks 0,1 (xl): 3-term split, Khat=3F. col-blocks 2,3 (xr): plain
// bf16 hi-only, Khat=F (logit-path precision is enough). 4 waves, 128x128
// block tile, 64x64 wave tile, BK=64. xl and xr both emitted as bf16.
template <int F>
__global__ __launch_bounds__(256) void gemm_mfma(const ushort* __restrict__ A2,
                                                 const ushort* __restrict__ WT,
                                                 ushort* __restrict__ xlb,
                                                 ushort* __restrict__ xrb, int n_nodes) {
  constexpr int KC = 3 * F;  // WT row stride
  __shared__ __align__(16) ushort As[128 * 64];
  __shared__ __align__(16) ushort Bs[128 * 64];
  const int tid = threadIdx.x;
  const int wv = tid >> 6, lane = tid & 63;
  const int m16 = lane & 15, quad = lane >> 4;
  const int col0 = blockIdx.x * 128;  // 0,1 -> xl ; 2,3 -> xr
  const int row0 = blockIdx.y * 128;
  const int wm = (wv >> 1) * 64, wn = (wv & 1) * 64;
  const bool is_xl = (col0 < 256);
  const int nstep = is_xl ? (3 * F) / 64 : F / 64;

  f32x4 acc[4][4];
#pragma unroll
  for (int i = 0; i < 4; ++i)
#pragma unroll
    for (int j = 0; j < 4; ++j) acc[i][j] = (f32x4){0.f, 0.f, 0.f, 0.f};

  for (int s = 0; s < nstep; ++s) {
    const int khat = s * 64;
    const int asrc = (khat < F) ? khat : khat - F;  // hi|hi|lo within A2 row
    __syncthreads();
#pragma unroll
    for (int t = 0; t < 4; ++t) {
      const int sl16 = tid + 256 * t;  // LDS slot (16B units), linear in lane
      const int row = sl16 >> 3, sl = sl16 & 7;
      const int gch = sl ^ (row & 7);  // swizzle on the GLOBAL address
      const int grow = row0 + row;
      if (grow < n_nodes)
        gl_lds16(A2 + (size_t)grow * (2 * F) + asrc + gch * 8, As + sl16 * 8);
      gl_lds16(WT + (size_t)(col0 + row) * KC + khat + gch * 8, Bs + sl16 * 8);
    }
    __syncthreads();
#pragma unroll
    for (int kh = 0; kh < 2; ++kh) {
      bf16x8 af[4], bf[4];
#pragma unroll
      for (int i = 0; i < 4; ++i) {
        const int row = wm + i * 16 + m16;
        const int slot = (kh * 4 + quad) ^ (row & 7);
        af[i] = *(bf16x8*)&As[row * 64 + slot * 8];
      }
#pragma unroll
      for (int j = 0; j < 4; ++j) {
        const int col = wn + j * 16 + m16;
        const int slot = (kh * 4 + quad) ^ (col & 7);
        bf[j] = *(bf16x8*)&Bs[col * 64 + slot * 8];
      }
#pragma unroll
      for (int i = 0; i < 4; ++i)
#pragma unroll
        for (int j = 0; j < 4; ++j)
          acc[i][j] =
              __builtin_amdgcn_mfma_f32_16x16x32_bf16(af[i], bf[j], acc[i][j], 0, 0, 0);
    }
  }
  // epilogue: C/D layout col=lane&15, row=quad*4+reg; both outputs bf16
#pragma unroll
  for (int i = 0; i < 4; ++i) {
#pragma unroll
    for (int r = 0; r < 4; ++r) {
      const int grow = row0 + wm + i * 16 + quad * 4 + r;
      if (grow < n_nodes) {
#pragma unroll
        for (int j = 0; j < 4; ++j) {
          const float v = acc[i][j][r];
          const int col = col0 + wn + j * 16 + m16;
          __hip_bfloat16 h = __float2bfloat16(v);
          if (is_xl)
            xlb[(size_t)grow * 256 + col] = *(ushort*)&h;
          else
            xrb[(size_t)grow * 256 + (col - 256)] = *(ushort*)&h;
        }
      }
    }
  }
}

// ================= CSR build (edges bucketed by dst) =======================
__global__ void k_hist(const int* __restrict__ ei, int* __restrict__ deg, int E_) {
  int e = blockIdx.x * blockDim.x + threadIdx.x;
  if (e < E_) atomicAdd(&deg[ei[E_ + e]], 1);
}

__global__ void k_scan_local(const int* __restrict__ deg, int* __restrict__ rowstart,
                             int* __restrict__ partial, int n) {
  __shared__ int a[256], b[256];
  const int t = threadIdx.x;
  const int i = blockIdx.x * 256 + t;
  const int v = (i < n) ? deg[i] : 0;
  a[t] = v;
  __syncthreads();
  int* cur = a;
  int* nxt = b;
  for (int off = 1; off < 256; off <<= 1) {
    int x = cur[t];
    if (t >= off) x += cur[t - off];
    nxt[t] = x;
    __syncthreads();
    int* tmp = cur; cur = nxt; nxt = tmp;
  }
  const int incl = cur[t];
  if (i < n) rowstart[i] = incl - v;
  if (t == 255) partial[blockIdx.x] = incl;
}

// single-block scan of block sums + zero-fill the 8-entry CSR pad
__global__ void k_scan_partial(int* __restrict__ partial, int nblk,
                               int* __restrict__ ssrc, float4* __restrict__ sea, int E_) {
  __shared__ int a[256], b[256];
  const int t = threadIdx.x;
  if (t < 8) {
    ssrc[E_ + t] = 0;
    sea[E_ + t] = make_float4(0.f, 0.f, 0.f, 0.f);
  }
  const int v = (t < nblk) ? partial[t] : 0;
  a[t] = v;
  __syncthreads();
  int* cur = a;
  int* nxt = b;
  for (int off = 1; off < 256; off <<= 1) {
    int x = cur[t];
    if (t >= off) x += cur[t - off];
    nxt[t] = x;
    __syncthreads();
    int* tmp = cur; cur = nxt; nxt = tmp;
  }
  if (t < nblk) partial[t] = cur[t] - v;
}

__global__ void k_add_off(int* __restrict__ rowstart, int* __restrict__ cursor,
                          const int* __restrict__ partial, int n, int E_) {
  int i = blockIdx.x * blockDim.x + threadIdx.x;
  if (i < n) {
    int v = rowstart[i] + partial[i >> 8];
    rowstart[i] = v;
    cursor[i] = v;
  }
  if (i == 0) rowstart[n] = E_;
}

// ==== fused: split x -> A2 (hi|lo) AND scatter edges into CSR order ========
__global__ void k_prep(const float* __restrict__ x, ushort* __restrict__ A2,
                       const int* __restrict__ ei, const float* __restrict__ ea,
                       int* __restrict__ cursor, int* __restrict__ ssrc,
                       float4* __restrict__ sea, int n, int E_) {
  const int nx4 = n * 128 / 4;
  int idx = blockIdx.x * blockDim.x + threadIdx.x;
  if (idx < nx4) {
    int row = idx >> 5, q = idx & 31;  // F=128 -> 32 float4 per row
    float4 v = ((const float4*)x)[idx];
    float vv[4] = {v.x, v.y, v.z, v.w};
    ushort hb[4], lb[4];
#pragma unroll
    for (int j = 0; j < 4; ++j) {
      __hip_bfloat16 h = __float2bfloat16(vv[j]);
      hb[j] = *(ushort*)&h;
      __hip_bfloat16 l = __float2bfloat16(vv[j] - __bfloat162float(h));
      lb[j] = *(ushort*)&l;
    }
    ushort* rp = A2 + (size_t)row * 256;
    *(ushort4*)(rp + q * 4) = make_ushort4(hb[0], hb[1], hb[2], hb[3]);
    *(ushort4*)(rp + 128 + q * 4) = make_ushort4(lb[0], lb[1], lb[2], lb[3]);
  } else {
    int e = idx - nx4;
    if (e < E_) {
      int dst = ei[E_ + e];
      int pos = atomicAdd(&cursor[dst], 1);
      ssrc[pos] = ei[e];
      sea[pos] = make_float4(ea[e * 3], ea[e * 3 + 1], ea[e * 3 + 2], 0.f);
    }
  }
}

// ================= fused per-destination attention =========================
// One wave per dst node (d wave-uniform -> scalar CSR/sea loads). 2-edge
// unroll, pad-based branch-free prefetch (no clamps). float2 channel math
// to coax v_pk_* packed ops. MODE 0: emit hi|lo bf16 split for next GEMM.
// MODE 1: fp32 + PReLU (final output).
__device__ __forceinline__ f32x2 vmax2(f32x2 a, f32x2 b) {
  return (f32x2){fmaxf(a.x, b.x), fmaxf(a.y, b.y)};
}
__device__ __forceinline__ f32x2 vmin2(f32x2 a, f32x2 b) {
  return (f32x2){fminf(a.x, b.x), fminf(a.y, b.y)};
}

__device__ __forceinline__ void edge_step(
    const ushort4& lu, const float4& eav, const f32x2* we0, const f32x2* we1,
    const f32x2* we2, const f32x2* at, const f32x2* xrl, f32x2& num01,
    f32x2& num23, float& den) {
  f32x2 lav0, lav1;
  lav0.x = __uint_as_float((unsigned)lu.x << 16);
  lav0.y = __uint_as_float((unsigned)lu.y << 16);
  lav1.x = __uint_as_float((unsigned)lu.z << 16);
  lav1.y = __uint_as_float((unsigned)lu.w << 16);
  const f32x2 zero = {0.f, 0.f};
  const f32x2 slope = {0.2f, 0.2f};
  f32x2 pv = zero;
#pragma unroll
  for (int j = 0; j < 2; ++j) {
    f32x2 la = (j == 0) ? lav0 : lav1;
    f32x2 ev = we0[j] * eav.x + we1[j] * eav.y + we2[j] * eav.z;
    f32x2 s = la + xrl[j] + ev;
    f32x2 z = vmax2(s, zero) + slope * vmin2(s, zero);
    pv = pv + z * at[j];
  }
  float p = pv.x + pv.y;
  p += __shfl_xor(p, 1);
  p += __shfl_xor(p, 2);
  p += __shfl_xor(p, 4);
  p += __shfl_xor(p, 8);
  const float w = __expf(p);  // |logit| << 80: no max-subtraction needed
  den += w;
  num01 = num01 + (f32x2){w, w} * lav0;
  num23 = num23 + (f32x2){w, w} * lav1;
}

template <int MODE>
__global__ __launch_bounds__(256) void fused_attn(
    const ushort* __restrict__ xlb, const ushort* __restrict__ xrb,
    const int* __restrict__ rowstart, const int* __restrict__ ssrc,
    const float4* __restrict__ sea, const float* __restrict__ We,
    const float* __restrict__ att, const float* __restrict__ bias,
    const float* __restrict__ pw, float* __restrict__ out,
    ushort* __restrict__ outs, int n) {
  const int lane = threadIdx.x & 63;
  const int d =
      __builtin_amdgcn_readfirstlane((blockIdx.x * blockDim.x + threadIdx.x) >> 6);
  if (d >= n) return;
  f32x2 we0[2], we1[2], we2[2], at[2];
#pragma unroll
  for (int j = 0; j < 4; ++j) {
    int r = 4 * lane + j;
    ((float*)we0)[j] = We[r * 3 + 0];
    ((float*)we1)[j] = We[r * 3 + 1];
    ((float*)we2)[j] = We[r * 3 + 2];
    ((float*)at)[j] = att[r];
  }
  const ushort4* xlb4 = (const ushort4*)xlb;
  const ushort4 xu = ((const ushort4*)xrb)[(unsigned)(d * 64) + lane];
  f32x2 xrl[2];
  xrl[0].x = __uint_as_float((unsigned)xu.x << 16);
  xrl[0].y = __uint_as_float((unsigned)xu.y << 16);
  xrl[1].x = __uint_as_float((unsigned)xu.z << 16);
  xrl[1].y = __uint_as_float((unsigned)xu.w << 16);

  int pos = rowstart[d];
  const int end = rowstart[d + 1];
  f32x2 num01 = {0.f, 0.f}, num23 = {0.f, 0.f};
  float den = 0.f;

  if (pos < end) {
    // CSR arrays are padded by 8 zero entries past E: unclamped prefetch safe
    int s0 = ssrc[pos], s1 = ssrc[pos + 1];
    ushort4 g0 = xlb4[(unsigned)(s0 * 64) + lane];
    ushort4 g1 = xlb4[(unsigned)(s1 * 64) + lane];
    float4 e0 = sea[pos], e1 = sea[pos + 1];
    int sn0 = ssrc[pos + 2], sn1 = ssrc[pos + 3];

    while (pos + 2 <= end) {
      ushort4 h0 = xlb4[(unsigned)(sn0 * 64) + lane];
      ushort4 h1 = xlb4[(unsigned)(sn1 * 64) + lane];
      float4 f0 = sea[pos + 2], f1 = sea[pos + 3];
      sn0 = ssrc[pos + 4];
      sn1 = ssrc[pos + 5];
      edge_step(g0, e0, we0, we1, we2, at, xrl, num01, num23, den);
      edge_step(g1, e1, we0, we1, we2, at, xrl, num01, num23, den);
      g0 = h0; g1 = h1; e0 = f0; e1 = f1;
      pos += 2;
    }
    if (pos < end)
      edge_step(g0, e0, we0, we1, we2, at, xrl, num01, num23, den);
  }

  const float inv = 1.f / (den + 1e-16f);
  float4 r;
  r.x = num01.x * inv;
  r.y = num01.y * inv;
  r.z = num23.x * inv;
  r.w = num23.y * inv;
  // combine the 4 heads: lanes {m, m+16, m+32, m+48} hold the same channels
  r.x += __shfl_xor(r.x, 16);
  r.y += __shfl_xor(r.y, 16);
  r.z += __shfl_xor(r.z, 16);
  r.w += __shfl_xor(r.w, 16);
  r.x += __shfl_xor(r.x, 32);
  r.y += __shfl_xor(r.y, 32);
  r.z += __shfl_xor(r.z, 32);
  r.w += __shfl_xor(r.w, 32);
  if (lane < 16) {
    const int c = 4 * lane;
    float o[4];
    o[0] = 0.25f * r.x + bias[c + 0];
    o[1] = 0.25f * r.y + bias[c + 1];
    o[2] = 0.25f * r.z + bias[c + 2];
    o[3] = 0.25f * r.w + bias[c + 3];
    if (MODE == 1) {
#pragma unroll
      for (int j = 0; j < 4; ++j) o[j] = (o[j] >= 0.f) ? o[j] : pw[c + j] * o[j];
      ((float4*)out)[(size_t)d * 16 + lane] = make_float4(o[0], o[1], o[2], o[3]);
    } else {
      // emit hi|lo bf16 split for next layer's GEMM: outs[d][128] = [hi64|lo64]
      ushort hb[4], lb[4];
#pragma unroll
      for (int j = 0; j < 4; ++j) {
        __hip_bfloat16 h = __float2bfloat16(o[j]);
        hb[j] = *(ushort*)&h;
        __hip_bfloat16 l = __float2bfloat16(o[j] - __bfloat162float(h));
        lb[j] = *(ushort*)&l;
      }
      *(ushort4*)(outs + (size_t)d * 128 + c) = make_ushort4(hb[0], hb[1], hb[2], hb[3]);
      *(ushort4*)(outs + (size_t)d * 128 + 64 + c) =
          make_ushort4(lb[0], lb[1], lb[2], lb[3]);
    }
  }
}

extern "C" void kernel_launch(void* const* d_in, const int* in_sizes, int n_in,
                              void* d_out, int out_size, void* d_ws, size_t ws_size,
                              hipStream_t stream) {
  const float* x    = (const float*)d_in[0];
  const int*   ei   = (const int*)d_in[1];
  const float* ea   = (const float*)d_in[2];
  const float* Wl1  = (const float*)d_in[3];
  const float* Wr1  = (const float*)d_in[4];
  const float* We1  = (const float*)d_in[5];
  const float* att1 = (const float*)d_in[6];
  const float* b1   = (const float*)d_in[7];
  const float* Wl2  = (const float*)d_in[8];
  const float* Wr2  = (const float*)d_in[9];
  const float* We2  = (const float*)d_in[10];
  const float* att2 = (const float*)d_in[11];
  const float* b2   = (const float*)d_in[12];
  const float* pw   = (const float*)d_in[13];
  const int N_ = in_sizes[0] / 128;
  const int E_ = in_sizes[1] / 2;
  float* out = (float*)d_out;

  char* w = (char*)d_ws;
  auto alloc = [&](size_t bytes) {
    char* p = w;
    w += (bytes + 255) & ~size_t(255);
    return p;
  };
  ushort* xlb      = (ushort*)alloc((size_t)N_ * 256 * 2);   // bf16 gather operand
  ushort* xrb      = (ushort*)alloc((size_t)N_ * 256 * 2);   // bf16 logit operand
  ushort* A2x      = (ushort*)alloc((size_t)N_ * 256 * 2);   // split of x (F=128)
  ushort* h2       = (ushort*)alloc((size_t)N_ * 128 * 2);   // split of h (F=64)
  int*    ssrc     = (int*)alloc((size_t)(E_ + 8) * 4);
  float4* sea      = (float4*)alloc((size_t)(E_ + 8) * 16);
  int*    deg      = (int*)alloc((size_t)N_ * 4);
  int*    rowstart = (int*)alloc((size_t)(N_ + 1) * 4);
  int*    cursor   = (int*)alloc((size_t)N_ * 4);
  int*    partial  = (int*)alloc(256 * 4);
  ushort* WT1      = (ushort*)alloc((size_t)512 * 384 * 2);
  ushort* WT2      = (ushort*)alloc((size_t)512 * 192 * 2);

  // ---- weight splits + deg zeroing (one kernel) ----
  const int wtot = 512 * 128 + 512 * 64 + N_;
  k_weights_deg<<<(wtot + 255) / 256, 256, 0, stream>>>(Wl1, Wr1, WT1, Wl2, Wr2, WT2,
                                                        deg, N_);

  // ---- CSR build + x split ----
  const int nblk = (N_ + 255) / 256;
  k_hist<<<(E_ + 255) / 256, 256, 0, stream>>>(ei, deg, E_);
  k_scan_local<<<nblk, 256, 0, stream>>>(deg, rowstart, partial, N_);
  k_scan_partial<<<1, 256, 0, stream>>>(partial, nblk, ssrc, sea, E_);
  k_add_off<<<nblk, 256, 0, stream>>>(rowstart, cursor, partial, N_, E_);
  const int ptot = N_ * 128 / 4 + E_;
  k_prep<<<(ptot + 255) / 256, 256, 0, stream>>>(x, A2x, ei, ea, cursor, ssrc, sea,
                                                 N_, E_);

  const dim3 GG(4, (N_ + 127) / 128);  // x: col-blocks (xl,xl,xr,xr); y: rows
  const int FB = (N_ + 3) / 4;         // fused: one wave per dst node

  // ---- layer 1 ----
  gemm_mfma<128><<<GG, 256, 0, stream>>>(A2x, WT1, xlb, xrb, N_);
  fused_attn<0><<<FB, 256, 0, stream>>>(xlb, xrb, rowstart, ssrc, sea, We1, att1,
                                        b1, pw, nullptr, h2, N_);
  // ---- layer 2 ----
  gemm_mfma<64><<<GG, 256, 0, stream>>>(h2, WT2, xlb, xrb, N_);
  fused_attn<1><<<FB, 256, 0, stream>>>(xlb, xrb, rowstart, ssrc, sea, We2, att2,
                                        b2, pw, out, nullptr, N_);
}

// Round 9
// 280.314 us; speedup vs baseline: 1.4420x; 1.0765x over previous
//
#include <hip/hip_runtime.h>
#include <hip/hip_bf16.h>

#define HC 256

typedef __attribute__((ext_vector_type(8))) short bf16x8;
typedef __attribute__((ext_vector_type(4))) float f32x4;
typedef __attribute__((ext_vector_type(2))) float f32x2;

__device__ __forceinline__ void gl_lds16(const void* g, void* l) {
  __builtin_amdgcn_global_load_lds(
      (const __attribute__((address_space(1))) unsigned int*)g,
      (__attribute__((address_space(3))) unsigned int*)l, 16, 0, 0);
}

// ==== bf16 weight casts for BOTH layers + deg zeroing, one kernel ==========
// WT[col][F]: col<256 from Wl, col>=256 from Wr (plain bf16, no split)
__device__ __forceinline__ void cast_w_one(const float* Wl, const float* Wr,
                                           ushort* WT, int F, int idx) {
  int col = idx / F, f = idx - col * F;
  float v = (col < 256) ? Wl[col * F + f] : Wr[(col - 256) * F + f];
  __hip_bfloat16 h = __float2bfloat16(v);
  WT[(size_t)col * F + f] = *(ushort*)&h;
}

__global__ void k_weights_deg(const float* __restrict__ Wl1, const float* __restrict__ Wr1,
                              ushort* __restrict__ WT1, const float* __restrict__ Wl2,
                              const float* __restrict__ Wr2, ushort* __restrict__ WT2,
                              int* __restrict__ deg, int n) {
  int idx = blockIdx.x * blockDim.x + threadIdx.x;
  const int t1 = 512 * 128, t2 = 512 * 64;
  if (idx < t1) {
    cast_w_one(Wl1, Wr1, WT1, 128, idx);
  } else if (idx < t1 + t2) {
    cast_w_one(Wl2, Wr2, WT2, 64, idx - t1);
  } else if (idx < t1 + t2 + n) {
    deg[idx - t1 - t2] = 0;
  }
}

// ======== MFMA GEMM (plain bf16, global_load_lds + XOR-swizzled LDS) =======
// All 512 output cols (xl|xr) at K=F. 4 waves, 128x128 block tile, 64x64
// wave tile, BK=64. LDS chunk c of row r stored at slot c^(r&7) (swizzle on
// the GLOBAL address; LDS stays linear-in-lane). Outputs bf16.
template <int F>
__global__ __launch_bounds__(256) void gemm_mfma(const ushort* __restrict__ A,
                                                 const ushort* __restrict__ WT,
                                                 ushort* __restrict__ xlb,
                                                 ushort* __restrict__ xrb, int n_nodes) {
  constexpr int NSTEP = F / 64;
  __shared__ __align__(16) ushort As[128 * 64];
  __shared__ __align__(16) ushort Bs[128 * 64];
  const int tid = threadIdx.x;
  const int wv = tid >> 6, lane = tid & 63;
  const int m16 = lane & 15, quad = lane >> 4;
  const int col0 = blockIdx.x * 128;  // 0,1 -> xl ; 2,3 -> xr
  const int row0 = blockIdx.y * 128;
  const int wm = (wv >> 1) * 64, wn = (wv & 1) * 64;

  f32x4 acc[4][4];
#pragma unroll
  for (int i = 0; i < 4; ++i)
#pragma unroll
    for (int j = 0; j < 4; ++j) acc[i][j] = (f32x4){0.f, 0.f, 0.f, 0.f};

#pragma unroll
  for (int s = 0; s < NSTEP; ++s) {
    const int khat = s * 64;
    __syncthreads();
#pragma unroll
    for (int t = 0; t < 4; ++t) {
      const int sl16 = tid + 256 * t;  // LDS slot (16B units), linear in lane
      const int row = sl16 >> 3, sl = sl16 & 7;
      const int gch = sl ^ (row & 7);  // swizzle on the GLOBAL address
      const int grow = row0 + row;
      if (grow < n_nodes)
        gl_lds16(A + (size_t)grow * F + khat + gch * 8, As + sl16 * 8);
      gl_lds16(WT + (size_t)(col0 + row) * F + khat + gch * 8, Bs + sl16 * 8);
    }
    __syncthreads();
#pragma unroll
    for (int kh = 0; kh < 2; ++kh) {
      bf16x8 af[4], bf[4];
#pragma unroll
      for (int i = 0; i < 4; ++i) {
        const int row = wm + i * 16 + m16;
        const int slot = (kh * 4 + quad) ^ (row & 7);
        af[i] = *(bf16x8*)&As[row * 64 + slot * 8];
      }
#pragma unroll
      for (int j = 0; j < 4; ++j) {
        const int col = wn + j * 16 + m16;
        const int slot = (kh * 4 + quad) ^ (col & 7);
        bf[j] = *(bf16x8*)&Bs[col * 64 + slot * 8];
      }
#pragma unroll
      for (int i = 0; i < 4; ++i)
#pragma unroll
        for (int j = 0; j < 4; ++j)
          acc[i][j] =
              __builtin_amdgcn_mfma_f32_16x16x32_bf16(af[i], bf[j], acc[i][j], 0, 0, 0);
    }
  }
  // epilogue: C/D layout col=lane&15, row=quad*4+reg; outputs bf16
  const bool is_xl = (col0 < 256);
#pragma unroll
  for (int i = 0; i < 4; ++i) {
#pragma unroll
    for (int r = 0; r < 4; ++r) {
      const int grow = row0 + wm + i * 16 + quad * 4 + r;
      if (grow < n_nodes) {
#pragma unroll
        for (int j = 0; j < 4; ++j) {
          const float v = acc[i][j][r];
          const int col = col0 + wn + j * 16 + m16;
          __hip_bfloat16 h = __float2bfloat16(v);
          if (is_xl)
            xlb[(size_t)grow * 256 + col] = *(ushort*)&h;
          else
            xrb[(size_t)grow * 256 + (col - 256)] = *(ushort*)&h;
        }
      }
    }
  }
}

// ================= CSR build (edges bucketed by dst) =======================
__global__ void k_hist(const int* __restrict__ ei, int* __restrict__ deg, int E_) {
  int e = blockIdx.x * blockDim.x + threadIdx.x;
  if (e < E_) atomicAdd(&deg[ei[E_ + e]], 1);
}

__global__ void k_scan_local(const int* __restrict__ deg, int* __restrict__ rowstart,
                             int* __restrict__ partial, int n) {
  __shared__ int a[256], b[256];
  const int t = threadIdx.x;
  const int i = blockIdx.x * 256 + t;
  const int v = (i < n) ? deg[i] : 0;
  a[t] = v;
  __syncthreads();
  int* cur = a;
  int* nxt = b;
  for (int off = 1; off < 256; off <<= 1) {
    int x = cur[t];
    if (t >= off) x += cur[t - off];
    nxt[t] = x;
    __syncthreads();
    int* tmp = cur; cur = nxt; nxt = tmp;
  }
  const int incl = cur[t];
  if (i < n) rowstart[i] = incl - v;
  if (t == 255) partial[blockIdx.x] = incl;
}

// single-block scan of block sums + zero-fill the 8-entry CSR pad
__global__ void k_scan_partial(int* __restrict__ partial, int nblk,
                               int* __restrict__ ssrc, float4* __restrict__ sea, int E_) {
  __shared__ int a[256], b[256];
  const int t = threadIdx.x;
  if (t < 8) {
    ssrc[E_ + t] = 0;
    sea[E_ + t] = make_float4(0.f, 0.f, 0.f, 0.f);
  }
  const int v = (t < nblk) ? partial[t] : 0;
  a[t] = v;
  __syncthreads();
  int* cur = a;
  int* nxt = b;
  for (int off = 1; off < 256; off <<= 1) {
    int x = cur[t];
    if (t >= off) x += cur[t - off];
    nxt[t] = x;
    __syncthreads();
    int* tmp = cur; cur = nxt; nxt = tmp;
  }
  if (t < nblk) partial[t] = cur[t] - v;
}

__global__ void k_add_off(int* __restrict__ rowstart, int* __restrict__ cursor,
                          const int* __restrict__ partial, int n, int E_) {
  int i = blockIdx.x * blockDim.x + threadIdx.x;
  if (i < n) {
    int v = rowstart[i] + partial[i >> 8];
    rowstart[i] = v;
    cursor[i] = v;
  }
  if (i == 0) rowstart[n] = E_;
}

// ==== fused: cast x -> bf16 A (row-major [n][128]) AND CSR edge scatter ====
__global__ void k_prep(const float* __restrict__ x, ushort* __restrict__ A,
                       const int* __restrict__ ei, const float* __restrict__ ea,
                       int* __restrict__ cursor, int* __restrict__ ssrc,
                       float4* __restrict__ sea, int n, int E_) {
  const int nx8 = n * 16;  // 8 elements per thread
  int idx = blockIdx.x * blockDim.x + threadIdx.x;
  if (idx < nx8) {
    const float4* xp = (const float4*)x + (size_t)idx * 2;
    float4 v0 = xp[0], v1 = xp[1];
    float vv[8] = {v0.x, v0.y, v0.z, v0.w, v1.x, v1.y, v1.z, v1.w};
    __align__(16) ushort hb[8];
#pragma unroll
    for (int j = 0; j < 8; ++j) {
      __hip_bfloat16 h = __float2bfloat16(vv[j]);
      hb[j] = *(ushort*)&h;
    }
    *(int4*)(A + (size_t)idx * 8) = *(int4*)hb;
  } else {
    int e = idx - nx8;
    if (e < E_) {
      int dst = ei[E_ + e];
      int pos = atomicAdd(&cursor[dst], 1);
      ssrc[pos] = ei[e];
      sea[pos] = make_float4(ea[e * 3], ea[e * 3 + 1], ea[e * 3 + 2], 0.f);
    }
  }
}

// ================= fused per-destination attention (persistent waves) ======
// Each wave owns a contiguous chunk of dst nodes: weight/bias prologue is
// amortized; CSR reads stream sequentially. 2-edge unroll, pad-based
// branch-free prefetch. MODE 0: emit bf16 h (next layer GEMM input).
// MODE 1: fp32 + PReLU (final output).
__device__ __forceinline__ f32x2 vmax2(f32x2 a, f32x2 b) {
  return (f32x2){fmaxf(a.x, b.x), fmaxf(a.y, b.y)};
}
__device__ __forceinline__ f32x2 vmin2(f32x2 a, f32x2 b) {
  return (f32x2){fminf(a.x, b.x), fminf(a.y, b.y)};
}

__device__ __forceinline__ void edge_step(
    const ushort4& lu, const float4& eav, const f32x2* we0, const f32x2* we1,
    const f32x2* we2, const f32x2* at, const f32x2* xrl, f32x2& num01,
    f32x2& num23, float& den) {
  f32x2 lav0, lav1;
  lav0.x = __uint_as_float((unsigned)lu.x << 16);
  lav0.y = __uint_as_float((unsigned)lu.y << 16);
  lav1.x = __uint_as_float((unsigned)lu.z << 16);
  lav1.y = __uint_as_float((unsigned)lu.w << 16);
  const f32x2 zero = {0.f, 0.f};
  const f32x2 slope = {0.2f, 0.2f};
  f32x2 pv = zero;
#pragma unroll
  for (int j = 0; j < 2; ++j) {
    f32x2 la = (j == 0) ? lav0 : lav1;
    f32x2 ev = we0[j] * eav.x + we1[j] * eav.y + we2[j] * eav.z;
    f32x2 s = la + xrl[j] + ev;
    f32x2 z = vmax2(s, zero) + slope * vmin2(s, zero);
    pv = pv + z * at[j];
  }
  float p = pv.x + pv.y;
  p += __shfl_xor(p, 1);
  p += __shfl_xor(p, 2);
  p += __shfl_xor(p, 4);
  p += __shfl_xor(p, 8);
  const float w = __expf(p);  // |logit| << 80: no max-subtraction needed
  den += w;
  num01 = num01 + (f32x2){w, w} * lav0;
  num23 = num23 + (f32x2){w, w} * lav1;
}

template <int MODE>
__global__ __launch_bounds__(256) void fused_attn(
    const ushort* __restrict__ xlb, const ushort* __restrict__ xrb,
    const int* __restrict__ rowstart, const int* __restrict__ ssrc,
    const float4* __restrict__ sea, const float* __restrict__ We,
    const float* __restrict__ att, const float* __restrict__ bias,
    const float* __restrict__ pw, float* __restrict__ out,
    ushort* __restrict__ outs, int n, int chunk) {
  const int lane = threadIdx.x & 63;
  const int wid =
      __builtin_amdgcn_readfirstlane((blockIdx.x * blockDim.x + threadIdx.x) >> 6);
  const int d0 = wid * chunk;
  if (d0 >= n) return;
  const int d1 = min(d0 + chunk, n);

  // ---- prologue (amortized over the chunk) ----
  f32x2 we0[2], we1[2], we2[2], at[2];
#pragma unroll
  for (int j = 0; j < 4; ++j) {
    int r = 4 * lane + j;
    ((float*)we0)[j] = We[r * 3 + 0];
    ((float*)we1)[j] = We[r * 3 + 1];
    ((float*)we2)[j] = We[r * 3 + 2];
    ((float*)at)[j] = att[r];
  }
  const float4 bias4 = ((const float4*)bias)[lane & 15];
  float4 pw4 = {0.f, 0.f, 0.f, 0.f};
  if (MODE == 1) pw4 = ((const float4*)pw)[lane & 15];
  const ushort4* xlb4 = (const ushort4*)xlb;

  for (int d = d0; d < d1; ++d) {
    const ushort4 xu = ((const ushort4*)xrb)[(unsigned)(d * 64) + lane];
    f32x2 xrl[2];
    xrl[0].x = __uint_as_float((unsigned)xu.x << 16);
    xrl[0].y = __uint_as_float((unsigned)xu.y << 16);
    xrl[1].x = __uint_as_float((unsigned)xu.z << 16);
    xrl[1].y = __uint_as_float((unsigned)xu.w << 16);

    int pos = rowstart[d];
    const int end = rowstart[d + 1];
    f32x2 num01 = {0.f, 0.f}, num23 = {0.f, 0.f};
    float den = 0.f;

    if (pos < end) {
      // CSR arrays padded by 8 zero entries past E: unclamped prefetch safe
      int s0 = ssrc[pos], s1 = ssrc[pos + 1];
      ushort4 g0 = xlb4[(unsigned)(s0 * 64) + lane];
      ushort4 g1 = xlb4[(unsigned)(s1 * 64) + lane];
      float4 e0 = sea[pos], e1 = sea[pos + 1];
      int sn0 = ssrc[pos + 2], sn1 = ssrc[pos + 3];

      while (pos + 2 <= end) {
        ushort4 h0 = xlb4[(unsigned)(sn0 * 64) + lane];
        ushort4 h1 = xlb4[(unsigned)(sn1 * 64) + lane];
        float4 f0 = sea[pos + 2], f1 = sea[pos + 3];
        sn0 = ssrc[pos + 4];
        sn1 = ssrc[pos + 5];
        edge_step(g0, e0, we0, we1, we2, at, xrl, num01, num23, den);
        edge_step(g1, e1, we0, we1, we2, at, xrl, num01, num23, den);
        g0 = h0; g1 = h1; e0 = f0; e1 = f1;
        pos += 2;
      }
      if (pos < end)
        edge_step(g0, e0, we0, we1, we2, at, xrl, num01, num23, den);
    }

    const float inv = 1.f / (den + 1e-16f);
    float4 r;
    r.x = num01.x * inv;
    r.y = num01.y * inv;
    r.z = num23.x * inv;
    r.w = num23.y * inv;
    // combine 4 heads: lanes {m, m+16, m+32, m+48} hold the same channels
    r.x += __shfl_xor(r.x, 16);
    r.y += __shfl_xor(r.y, 16);
    r.z += __shfl_xor(r.z, 16);
    r.w += __shfl_xor(r.w, 16);
    r.x += __shfl_xor(r.x, 32);
    r.y += __shfl_xor(r.y, 32);
    r.z += __shfl_xor(r.z, 32);
    r.w += __shfl_xor(r.w, 32);
    if (lane < 16) {
      float o[4];
      o[0] = 0.25f * r.x + bias4.x;
      o[1] = 0.25f * r.y + bias4.y;
      o[2] = 0.25f * r.z + bias4.z;
      o[3] = 0.25f * r.w + bias4.w;
      if (MODE == 1) {
        const float pwv[4] = {pw4.x, pw4.y, pw4.z, pw4.w};
#pragma unroll
        for (int j = 0; j < 4; ++j) o[j] = (o[j] >= 0.f) ? o[j] : pwv[j] * o[j];
        ((float4*)out)[(size_t)d * 16 + lane] = make_float4(o[0], o[1], o[2], o[3]);
      } else {
        ushort hb[4];
#pragma unroll
        for (int j = 0; j < 4; ++j) {
          __hip_bfloat16 h = __float2bfloat16(o[j]);
          hb[j] = *(ushort*)&h;
        }
        *(ushort4*)(outs + (size_t)d * 64 + 4 * lane) =
            make_ushort4(hb[0], hb[1], hb[2], hb[3]);
      }
    }
  }
}

extern "C" void kernel_launch(void* const* d_in, const int* in_sizes, int n_in,
                              void* d_out, int out_size, void* d_ws, size_t ws_size,
                              hipStream_t stream) {
  const float* x    = (const float*)d_in[0];
  const int*   ei   = (const int*)d_in[1];
  const float* ea   = (const float*)d_in[2];
  const float* Wl1  = (const float*)d_in[3];
  const float* Wr1  = (const float*)d_in[4];
  const float* We1  = (const float*)d_in[5];
  const float* att1 = (const float*)d_in[6];
  const float* b1   = (const float*)d_in[7];
  const float* Wl2  = (const float*)d_in[8];
  const float* Wr2  = (const float*)d_in[9];
  const float* We2  = (const float*)d_in[10];
  const float* att2 = (const float*)d_in[11];
  const float* b2   = (const float*)d_in[12];
  const float* pw   = (const float*)d_in[13];
  const int N_ = in_sizes[0] / 128;
  const int E_ = in_sizes[1] / 2;
  float* out = (float*)d_out;

  char* w = (char*)d_ws;
  auto alloc = [&](size_t bytes) {
    char* p = w;
    w += (bytes + 255) & ~size_t(255);
    return p;
  };
  ushort* xlb      = (ushort*)alloc((size_t)N_ * 256 * 2);   // bf16 gather operand
  ushort* xrb      = (ushort*)alloc((size_t)N_ * 256 * 2);   // bf16 logit operand
  ushort* Ax       = (ushort*)alloc((size_t)N_ * 128 * 2);   // bf16 cast of x
  ushort* h2       = (ushort*)alloc((size_t)N_ * 64 * 2);    // bf16 h (layer-2 A)
  int*    ssrc     = (int*)alloc((size_t)(E_ + 8) * 4);
  float4* sea      = (float4*)alloc((size_t)(E_ + 8) * 16);
  int*    deg      = (int*)alloc((size_t)N_ * 4);
  int*    rowstart = (int*)alloc((size_t)(N_ + 1) * 4);
  int*    cursor   = (int*)alloc((size_t)N_ * 4);
  int*    partial  = (int*)alloc(256 * 4);
  ushort* WT1      = (ushort*)alloc((size_t)512 * 128 * 2);
  ushort* WT2      = (ushort*)alloc((size_t)512 * 64 * 2);

  // ---- weight casts + deg zeroing (one kernel) ----
  const int wtot = 512 * 128 + 512 * 64 + N_;
  k_weights_deg<<<(wtot + 255) / 256, 256, 0, stream>>>(Wl1, Wr1, WT1, Wl2, Wr2, WT2,
                                                        deg, N_);

  // ---- CSR build + x cast ----
  const int nblk = (N_ + 255) / 256;
  k_hist<<<(E_ + 255) / 256, 256, 0, stream>>>(ei, deg, E_);
  k_scan_local<<<nblk, 256, 0, stream>>>(deg, rowstart, partial, N_);
  k_scan_partial<<<1, 256, 0, stream>>>(partial, nblk, ssrc, sea, E_);
  k_add_off<<<nblk, 256, 0, stream>>>(rowstart, cursor, partial, N_, E_);
  const int ptot = N_ * 16 + E_;
  k_prep<<<(ptot + 255) / 256, 256, 0, stream>>>(x, Ax, ei, ea, cursor, ssrc, sea,
                                                 N_, E_);

  const dim3 GG(4, (N_ + 127) / 128);  // x: col-blocks (xl,xl,xr,xr); y: rows
  const int FW = 8192;                 // persistent waves
  const int FB = FW / 4;               // 4 waves per block
  const int chunk = (N_ + FW - 1) / FW;

  // ---- layer 1 ----
  gemm_mfma<128><<<GG, 256, 0, stream>>>(Ax, WT1, xlb, xrb, N_);
  fused_attn<0><<<FB, 256, 0, stream>>>(xlb, xrb, rowstart, ssrc, sea, We1, att1,
                                        b1, pw, nullptr, h2, N_, chunk);
  // ---- layer 2 ----
  gemm_mfma<64><<<GG, 256, 0, stream>>>(h2, WT2, xlb, xrb, N_);
  fused_attn<1><<<FB, 256, 0, stream>>>(xlb, xrb, rowstart, ssrc, sea, We2, att2,
                                        b2, pw, out, nullptr, N_, chunk);
}